// Round 1
// baseline (256.835 us; speedup 1.0000x reference)
//
#include <hip/hip_runtime.h>

typedef __bf16 bf16_8 __attribute__((ext_vector_type(8)));
typedef __bf16 bf16_4 __attribute__((ext_vector_type(4)));
typedef float  f32x4  __attribute__((ext_vector_type(4)));

#define NB 32
#define NT 2048
#define NC 384
#define NH 64

static __device__ __forceinline__ f32x4 mfma16(bf16_8 a, bf16_8 b, f32x4 c) {
  return __builtin_amdgcn_mfma_f32_16x16x32_bf16(a, b, c, 0, 0, 0);
}

// ---- kernel 1: pack weights: fp32 [C,H] x3 -> bf16 Wt[n][k], n: 0-63=Q(Wq*0.125), 64-127=K, 128-191=V
__global__ void pack_w_kernel(const float* __restrict__ Wk, const float* __restrict__ Wq,
                              const float* __restrict__ Wv, __bf16* __restrict__ Wt) {
  int idx = blockIdx.x * 256 + threadIdx.x;
  if (idx >= 192 * NC) return;
  int n = idx / NC, k = idx % NC;
  int sel = n >> 6, h = n & 63;
  const float* W = (sel == 0) ? Wq : (sel == 1 ? Wk : Wv);
  float v = W[k * NH + h];
  if (sel == 0) v *= 0.125f;  // fold attention scale H^-0.5 (exact pow2)
  Wt[idx] = (__bf16)v;
}

// ---- kernel 2: QKV projection. M=B*T=65536, K=384, N=192. 128 rows/block, 4 waves x 32 rows.
// Writes Q[b][t][h], K[b][t][h] bf16; V transposed to Vt[b][h][t] bf16 via LDS.
__launch_bounds__(256)
__global__ void qkv_kernel(const float* __restrict__ x, const __bf16* __restrict__ Wt,
                           __bf16* __restrict__ Q, __bf16* __restrict__ K,
                           __bf16* __restrict__ Vt) {
  __shared__ __bf16 Vl[64][136];  // [h][t_local 128 + pad8]

  const int tid  = threadIdx.x;
  const int lane = tid & 63, wq = tid >> 6;
  const int quad = lane >> 4, l16 = lane & 15;
  const int rowblk = blockIdx.x * 128;
  const int rbase  = rowblk + wq * 32;  // wave's 32 rows (2 m-tiles)

  f32x4 acc[2][12];
  #pragma unroll
  for (int m = 0; m < 2; ++m)
    #pragma unroll
    for (int n = 0; n < 12; ++n) acc[m][n] = f32x4{0.f, 0.f, 0.f, 0.f};

  for (int kc = 0; kc < 12; ++kc) {
    const int k0 = kc * 32 + quad * 8;
    bf16_8 a[2];
    #pragma unroll
    for (int m = 0; m < 2; ++m) {
      const float* xp = x + (size_t)(rbase + m * 16 + l16) * NC + k0;
      f32x4 x0 = *(const f32x4*)xp;
      f32x4 x1 = *(const f32x4*)(xp + 4);
      bf16_8 t;
      t[0] = (__bf16)x0[0]; t[1] = (__bf16)x0[1]; t[2] = (__bf16)x0[2]; t[3] = (__bf16)x0[3];
      t[4] = (__bf16)x1[0]; t[5] = (__bf16)x1[1]; t[6] = (__bf16)x1[2]; t[7] = (__bf16)x1[3];
      a[m] = t;
    }
    #pragma unroll
    for (int n = 0; n < 12; ++n) {
      bf16_8 b = *(const bf16_8*)(Wt + (size_t)(n * 16 + l16) * NC + k0);
      acc[0][n] = mfma16(a[0], b, acc[0][n]);
      acc[1][n] = mfma16(a[1], b, acc[1][n]);
    }
  }

  // epilogue: Q, K direct stores (C-layout: row=quad*4+r, col=l16)
  #pragma unroll
  for (int m = 0; m < 2; ++m)
    #pragma unroll
    for (int n = 0; n < 8; ++n)
      #pragma unroll
      for (int r = 0; r < 4; ++r) {
        int row = rbase + m * 16 + quad * 4 + r;
        int h = (n & 3) * 16 + l16;
        __bf16 bv = (__bf16)acc[m][n][r];
        if (n < 4) Q[(size_t)row * NH + h] = bv;
        else       K[(size_t)row * NH + h] = bv;
      }

  // V: lane holds 4 consecutive t (regs) at fixed h -> contiguous 8B LDS write transposed
  #pragma unroll
  for (int m = 0; m < 2; ++m)
    #pragma unroll
    for (int n = 8; n < 12; ++n) {
      int h = (n - 8) * 16 + l16;
      int t0 = wq * 32 + m * 16 + quad * 4;
      bf16_4 p;
      p[0] = (__bf16)acc[m][n][0]; p[1] = (__bf16)acc[m][n][1];
      p[2] = (__bf16)acc[m][n][2]; p[3] = (__bf16)acc[m][n][3];
      *(bf16_4*)&Vl[h][t0] = p;
    }
  __syncthreads();
  // coalesced write-out: Vt[b][h][t]
  {
    int h = tid >> 2, seg = tid & 3;
    int bb = rowblk >> 11, t0 = (rowblk & (NT - 1)) + seg * 32;
    const __bf16* src = &Vl[h][seg * 32];
    __bf16* dst = Vt + ((size_t)(bb * NH + h)) * NT + t0;
    #pragma unroll
    for (int i = 0; i < 4; ++i) ((uint4*)dst)[i] = ((const uint4*)src)[i];
  }
}

// ---- kernel 3: flash attention. BM=BN=64, 4 waves x 16 q-rows.
// Computes S^T = K*Q^T so softmax rows live in-lane (col=lane&15=q).
__launch_bounds__(256)
__global__ void attn_kernel(const __bf16* __restrict__ Q, const __bf16* __restrict__ K,
                            const __bf16* __restrict__ Vt, float* __restrict__ out) {
  __shared__ __bf16 Ks[64][72];       // [s][h]
  __shared__ __bf16 Vs[64][72];       // [h][s]
  __shared__ __bf16 Ps[4][16][72];    // per-wave P[q][s]

  const int tid  = threadIdx.x;
  const int lane = tid & 63, wq = tid >> 6;
  const int quad = lane >> 4, l16 = lane & 15;
  const int b  = blockIdx.x >> 5;
  const int qt = 31 - (blockIdx.x & 31);  // heavy tiles dispatch first
  const int q0 = qt * 64;

  const float NEG_INF = -__builtin_inff();

  // Q B-operand fragments: b_frag[j] = Q[q0+wq*16+l16][kk*32+quad*8+j] (scale pre-folded)
  const __bf16* qrow = Q + ((size_t)(b * NT + q0 + wq * 16 + l16)) * NH + quad * 8;
  bf16_8 qf0 = *(const bf16_8*)qrow;
  bf16_8 qf1 = *(const bf16_8*)(qrow + 32);

  f32x4 o[4];
  #pragma unroll
  for (int i = 0; i < 4; ++i) o[i] = f32x4{0.f, 0.f, 0.f, 0.f};
  float m_i = NEG_INF, l_i = 0.f;

  const int r = tid >> 2, seg = tid & 3;  // staging: 4 threads per 64-elem row
  const __bf16* Kg = K  + (size_t)b * NT * NH;
  const __bf16* Vg = Vt + (size_t)b * NH * NT;

  for (int s0 = 0; s0 <= q0; s0 += 64) {
    __syncthreads();  // previous iteration's readers done before restage
    {
      const uint4* sK = (const uint4*)(Kg + (size_t)(s0 + r) * NH + seg * 16);
      uint4 k0v = sK[0], k1v = sK[1];
      *(uint4*)&Ks[r][seg * 16]     = k0v;
      *(uint4*)&Ks[r][seg * 16 + 8] = k1v;
      const uint4* sV = (const uint4*)(Vg + (size_t)r * NT + s0 + seg * 16);
      uint4 v0v = sV[0], v1v = sV[1];
      *(uint4*)&Vs[r][seg * 16]     = v0v;
      *(uint4*)&Vs[r][seg * 16 + 8] = v1v;
    }
    __syncthreads();

    // S^T tiles: A=K rows (m=s), B=Q^T (n=q). D[s=quad*4+r][q=l16]
    f32x4 s[4];
    #pragma unroll
    for (int st = 0; st < 4; ++st) {
      bf16_8 a0 = *(const bf16_8*)&Ks[st * 16 + l16][quad * 8];
      bf16_8 a1 = *(const bf16_8*)&Ks[st * 16 + l16][quad * 8 + 32];
      f32x4 accv = f32x4{0.f, 0.f, 0.f, 0.f};
      accv = mfma16(a0, qf0, accv);
      accv = mfma16(a1, qf1, accv);
      s[st] = accv;
    }

    if (s0 == q0) {  // diagonal tile: causal mask (wave-uniform branch)
      int qg = wq * 16 + l16;
      #pragma unroll
      for (int st = 0; st < 4; ++st)
        #pragma unroll
        for (int rr = 0; rr < 4; ++rr) {
          int sg = st * 16 + quad * 4 + rr;
          if (sg > qg) s[st][rr] = NEG_INF;
        }
    }

    // online softmax: all 16 values in-lane share q=l16
    float mx = NEG_INF;
    #pragma unroll
    for (int st = 0; st < 4; ++st)
      #pragma unroll
      for (int rr = 0; rr < 4; ++rr) mx = fmaxf(mx, s[st][rr]);
    mx = fmaxf(mx, __shfl_xor(mx, 16));
    mx = fmaxf(mx, __shfl_xor(mx, 32));
    float m_new = fmaxf(m_i, mx);
    float alpha = __expf(m_i - m_new);  // exp(-inf)=0 on first iter

    float lsum = 0.f;
    #pragma unroll
    for (int st = 0; st < 4; ++st) {
      bf16_4 pk;
      #pragma unroll
      for (int rr = 0; rr < 4; ++rr) {
        float p = __expf(s[st][rr] - m_new);
        lsum += p;
        pk[rr] = (__bf16)p;
      }
      *(bf16_4*)&Ps[wq][l16][st * 16 + quad * 4] = pk;  // P[q][s], 4 consecutive s
    }
    lsum += __shfl_xor(lsum, 16);
    lsum += __shfl_xor(lsum, 32);
    l_i = l_i * alpha + lsum;
    m_i = m_new;

    // rescale O (C-layout row q = quad*4+rr): fetch alpha from lane q
    f32x4 av;
    #pragma unroll
    for (int rr = 0; rr < 4; ++rr) av[rr] = __shfl(alpha, quad * 4 + rr);
    #pragma unroll
    for (int nt = 0; nt < 4; ++nt)
      #pragma unroll
      for (int rr = 0; rr < 4; ++rr) o[nt][rr] *= av[rr];

    // PV: A = P (own wave's LDS, no barrier), B = V from Vs[h][s]
    bf16_8 pa0 = *(const bf16_8*)&Ps[wq][l16][quad * 8];
    bf16_8 pa1 = *(const bf16_8*)&Ps[wq][l16][quad * 8 + 32];
    #pragma unroll
    for (int nt = 0; nt < 4; ++nt) {
      bf16_8 b0 = *(const bf16_8*)&Vs[nt * 16 + l16][quad * 8];
      bf16_8 b1 = *(const bf16_8*)&Vs[nt * 16 + l16][quad * 8 + 32];
      o[nt] = mfma16(pa0, b0, o[nt]);
      o[nt] = mfma16(pa1, b1, o[nt]);
    }
  }

  // epilogue: divide by l, store fp32
  f32x4 lv;
  #pragma unroll
  for (int rr = 0; rr < 4; ++rr) lv[rr] = 1.f / __shfl(l_i, quad * 4 + rr);
  float* op = out + ((size_t)(b * NT + q0 + wq * 16 + quad * 4)) * NH + l16;
  #pragma unroll
  for (int nt = 0; nt < 4; ++nt)
    #pragma unroll
    for (int rr = 0; rr < 4; ++rr)
      op[(size_t)rr * NH + nt * 16] = o[nt][rr] * lv[rr];
}

extern "C" void kernel_launch(void* const* d_in, const int* in_sizes, int n_in,
                              void* d_out, int out_size, void* d_ws, size_t ws_size,
                              hipStream_t stream) {
  const float* x  = (const float*)d_in[0];
  const float* Wk = (const float*)d_in[1];
  const float* Wq = (const float*)d_in[2];
  const float* Wv = (const float*)d_in[3];
  float* out = (float*)d_out;

  char* ws = (char*)d_ws;
  __bf16* Wt  = (__bf16*)ws;                       // 192*384*2 = 147,456 B
  __bf16* Qb  = (__bf16*)(ws + 256 * 1024);        // each 32*2048*64*2 = 8 MiB
  __bf16* Kb  = Qb + (size_t)NB * NT * NH;
  __bf16* Vtb = Kb + (size_t)NB * NT * NH;

  pack_w_kernel<<<288, 256, 0, stream>>>(Wk, Wq, Wv, Wt);
  qkv_kernel<<<512, 256, 0, stream>>>(x, Wt, Qb, Kb, Vtb);
  attn_kernel<<<NB * 32, 256, 0, stream>>>(Qb, Kb, Vtb, out);
}

// Round 2
// 251.256 us; speedup vs baseline: 1.0222x; 1.0222x over previous
//
#include <hip/hip_runtime.h>

typedef __bf16 bf16_8 __attribute__((ext_vector_type(8)));
typedef __bf16 bf16_4 __attribute__((ext_vector_type(4)));
typedef float  f32x4  __attribute__((ext_vector_type(4)));

#define NB 32
#define NT 2048
#define NC 384
#define NH 64

static __device__ __forceinline__ f32x4 mfma16(bf16_8 a, bf16_8 b, f32x4 c) {
  return __builtin_amdgcn_mfma_f32_16x16x32_bf16(a, b, c, 0, 0, 0);
}

// ---- kernel 1: pack weights: fp32 [C,H] x3 -> bf16 Wt[n][k], n: 0-63=Q(Wq*0.125), 64-127=K, 128-191=V
__global__ void pack_w_kernel(const float* __restrict__ Wk, const float* __restrict__ Wq,
                              const float* __restrict__ Wv, __bf16* __restrict__ Wt) {
  int idx = blockIdx.x * 256 + threadIdx.x;
  if (idx >= 192 * NC) return;
  int n = idx / NC, k = idx % NC;
  int sel = n >> 6, h = n & 63;
  const float* W = (sel == 0) ? Wq : (sel == 1 ? Wk : Wv);
  float v = W[k * NH + h];
  if (sel == 0) v *= 0.125f;  // fold attention scale H^-0.5 (exact pow2)
  Wt[idx] = (__bf16)v;
}

// ---- kernel 2: QKV projection. 64 rows/block, 4 waves x 1 m-tile (16 rows).
// Light register footprint (acc=48 VGPR) so the kc-loop pipelines; x prefetched 1 ahead.
__launch_bounds__(256, 4)
__global__ void qkv_kernel(const float* __restrict__ x, const __bf16* __restrict__ Wt,
                           __bf16* __restrict__ Q, __bf16* __restrict__ K,
                           __bf16* __restrict__ Vt) {
  __shared__ __bf16 Vl[64][72];  // [h][t_local 64 + pad8]

  const int tid  = threadIdx.x;
  const int lane = tid & 63, wq = tid >> 6;
  const int quad = lane >> 4, l16 = lane & 15;
  const int rowblk = blockIdx.x * 64;
  const int rbase  = rowblk + wq * 16;

  f32x4 acc[12];
  #pragma unroll
  for (int n = 0; n < 12; ++n) acc[n] = f32x4{0.f, 0.f, 0.f, 0.f};

  const float* xrow = x + (size_t)(rbase + l16) * NC;
  f32x4 x0 = *(const f32x4*)(xrow + quad * 8);
  f32x4 x1 = *(const f32x4*)(xrow + quad * 8 + 4);

  for (int kc = 0; kc < 12; ++kc) {
    f32x4 nx0, nx1;
    if (kc < 11) {  // prefetch next x slab (HBM) before the MFMA chain
      const float* xp = xrow + (kc + 1) * 32 + quad * 8;
      nx0 = *(const f32x4*)xp;
      nx1 = *(const f32x4*)(xp + 4);
    }
    bf16_8 a;
    a[0] = (__bf16)x0[0]; a[1] = (__bf16)x0[1]; a[2] = (__bf16)x0[2]; a[3] = (__bf16)x0[3];
    a[4] = (__bf16)x1[0]; a[5] = (__bf16)x1[1]; a[6] = (__bf16)x1[2]; a[7] = (__bf16)x1[3];
    const __bf16* wp = Wt + (size_t)l16 * NC + kc * 32 + quad * 8;
    #pragma unroll
    for (int n = 0; n < 12; ++n) {
      bf16_8 b = *(const bf16_8*)(wp + (size_t)n * 16 * NC);
      acc[n] = mfma16(a, b, acc[n]);
    }
    x0 = nx0; x1 = nx1;
  }

  // Q, K direct stores (C-layout: row=quad*4+r, col=l16)
  #pragma unroll
  for (int n = 0; n < 8; ++n)
    #pragma unroll
    for (int r = 0; r < 4; ++r) {
      int row = rbase + quad * 4 + r;
      int h = (n & 3) * 16 + l16;
      __bf16 bv = (__bf16)acc[n][r];
      if (n < 4) Q[(size_t)row * NH + h] = bv;
      else       K[(size_t)row * NH + h] = bv;
    }

  // V: lane holds 4 consecutive t at fixed h -> 8B LDS write transposed
  #pragma unroll
  for (int n = 8; n < 12; ++n) {
    int h = (n - 8) * 16 + l16;
    int t0 = wq * 16 + quad * 4;
    bf16_4 p;
    p[0] = (__bf16)acc[n][0]; p[1] = (__bf16)acc[n][1];
    p[2] = (__bf16)acc[n][2]; p[3] = (__bf16)acc[n][3];
    *(bf16_4*)&Vl[h][t0] = p;
  }
  __syncthreads();
  {
    int h = tid >> 2, seg = tid & 3;
    int bb = rowblk >> 11, t0 = (rowblk & (NT - 1)) + seg * 16;
    const __bf16* src = &Vl[h][seg * 16];
    __bf16* dst = Vt + ((size_t)(bb * NH + h)) * NT + t0;
    ((uint4*)dst)[0] = ((const uint4*)src)[0];
    ((uint4*)dst)[1] = ((const uint4*)src)[1];
  }
}

// ---- kernel 3: flash attention, fold-paired for uniform work.
// Block handles q-tiles (31-pair) then (pair): total 33 s-iterations every block.
// Double-buffered K/V staging: one barrier per iteration, loads in flight across it.
__launch_bounds__(256)
__global__ void attn_kernel(const __bf16* __restrict__ Q, const __bf16* __restrict__ K,
                            const __bf16* __restrict__ Vt, float* __restrict__ out) {
  __shared__ __bf16 Ks[2][64][72];    // [buf][s][h]
  __shared__ __bf16 Vs[2][64][72];    // [buf][h][s]
  __shared__ __bf16 Ps[4][16][72];    // per-wave P[q][s]

  const int tid  = threadIdx.x;
  const int lane = tid & 63, wq = tid >> 6;
  const int quad = lane >> 4, l16 = lane & 15;
  const int b    = blockIdx.x >> 4;
  const int pair = blockIdx.x & 15;

  const float NEG_INF = -__builtin_inff();
  const int r = tid >> 2, seg = tid & 3;  // staging: 4 threads per 64-elem row
  const __bf16* Kg = K  + (size_t)b * NT * NH;
  const __bf16* Vg = Vt + (size_t)b * NH * NT;

  for (int pass = 0; pass < 2; ++pass) {
    const int qt = pass ? pair : (31 - pair);
    const int q0 = qt * 64;
    const int nIter = qt + 1;

    // Q B-operand fragments (scale pre-folded into Wq)
    const __bf16* qrow = Q + ((size_t)(b * NT + q0 + wq * 16 + l16)) * NH + quad * 8;
    bf16_8 qf0 = *(const bf16_8*)qrow;
    bf16_8 qf1 = *(const bf16_8*)(qrow + 32);

    f32x4 o[4];
    #pragma unroll
    for (int i = 0; i < 4; ++i) o[i] = f32x4{0.f, 0.f, 0.f, 0.f};
    float m_i = NEG_INF, l_i = 0.f;

    __syncthreads();  // previous pass's readers done before restaging buf0

    // prologue: stage tile 0 into buf 0
    {
      const uint4* sK = (const uint4*)(Kg + (size_t)r * NH + seg * 16);
      uint4 ka = sK[0], kb = sK[1];
      const uint4* sV = (const uint4*)(Vg + (size_t)r * NT + seg * 16);
      uint4 va = sV[0], vb = sV[1];
      *(uint4*)&Ks[0][r][seg * 16]     = ka;
      *(uint4*)&Ks[0][r][seg * 16 + 8] = kb;
      *(uint4*)&Vs[0][r][seg * 16]     = va;
      *(uint4*)&Vs[0][r][seg * 16 + 8] = vb;
    }

    for (int i = 0; i < nIter; ++i) {
      const int cur = i & 1;
      const bool more = (i + 1 < nIter);
      uint4 nka, nkb, nva, nvb;
      if (more) {  // issue next tile's global loads; they fly across the barrier
        const int s0n = (i + 1) * 64;
        const uint4* sK = (const uint4*)(Kg + (size_t)(s0n + r) * NH + seg * 16);
        nka = sK[0]; nkb = sK[1];
        const uint4* sV = (const uint4*)(Vg + (size_t)r * NT + s0n + seg * 16);
        nva = sV[0]; nvb = sV[1];
      }
      __syncthreads();  // buf[cur] fully staged

      // S^T tiles: A=K rows (m=s), B=Q^T (n=q). D[s=quad*4+rr][q=l16]
      f32x4 s[4];
      #pragma unroll
      for (int st = 0; st < 4; ++st) {
        bf16_8 a0 = *(const bf16_8*)&Ks[cur][st * 16 + l16][quad * 8];
        bf16_8 a1 = *(const bf16_8*)&Ks[cur][st * 16 + l16][quad * 8 + 32];
        f32x4 accv = f32x4{0.f, 0.f, 0.f, 0.f};
        accv = mfma16(a0, qf0, accv);
        accv = mfma16(a1, qf1, accv);
        s[st] = accv;
      }

      if (i == qt) {  // diagonal tile: causal mask
        int qg = wq * 16 + l16;
        #pragma unroll
        for (int st = 0; st < 4; ++st)
          #pragma unroll
          for (int rr = 0; rr < 4; ++rr) {
            int sg = st * 16 + quad * 4 + rr;
            if (sg > qg) s[st][rr] = NEG_INF;
          }
      }

      // online softmax: all 16 values in-lane share q=l16
      float mx = NEG_INF;
      #pragma unroll
      for (int st = 0; st < 4; ++st)
        #pragma unroll
        for (int rr = 0; rr < 4; ++rr) mx = fmaxf(mx, s[st][rr]);
      mx = fmaxf(mx, __shfl_xor(mx, 16));
      mx = fmaxf(mx, __shfl_xor(mx, 32));
      float m_new = fmaxf(m_i, mx);
      float alpha = __expf(m_i - m_new);

      float lsum = 0.f;
      #pragma unroll
      for (int st = 0; st < 4; ++st) {
        bf16_4 pk;
        #pragma unroll
        for (int rr = 0; rr < 4; ++rr) {
          float p = __expf(s[st][rr] - m_new);
          lsum += p;
          pk[rr] = (__bf16)p;
        }
        *(bf16_4*)&Ps[wq][l16][st * 16 + quad * 4] = pk;
      }
      lsum += __shfl_xor(lsum, 16);
      lsum += __shfl_xor(lsum, 32);
      l_i = l_i * alpha + lsum;
      m_i = m_new;

      // rescale O (C-layout row q = quad*4+rr)
      f32x4 av;
      #pragma unroll
      for (int rr = 0; rr < 4; ++rr) av[rr] = __shfl(alpha, quad * 4 + rr);
      #pragma unroll
      for (int nt = 0; nt < 4; ++nt)
        #pragma unroll
        for (int rr = 0; rr < 4; ++rr) o[nt][rr] *= av[rr];

      // PV: A = P (own wave's LDS), B = V from Vs[cur][h][s]
      bf16_8 pa0 = *(const bf16_8*)&Ps[wq][l16][quad * 8];
      bf16_8 pa1 = *(const bf16_8*)&Ps[wq][l16][quad * 8 + 32];
      #pragma unroll
      for (int nt = 0; nt < 4; ++nt) {
        bf16_8 b0 = *(const bf16_8*)&Vs[cur][nt * 16 + l16][quad * 8];
        bf16_8 b1 = *(const bf16_8*)&Vs[cur][nt * 16 + l16][quad * 8 + 32];
        o[nt] = mfma16(pa0, b0, o[nt]);
        o[nt] = mfma16(pa1, b1, o[nt]);
      }

      if (more) {  // write next tile into the other buffer (no one reads it now)
        *(uint4*)&Ks[1 - cur][r][seg * 16]     = nka;
        *(uint4*)&Ks[1 - cur][r][seg * 16 + 8] = nkb;
        *(uint4*)&Vs[1 - cur][r][seg * 16]     = nva;
        *(uint4*)&Vs[1 - cur][r][seg * 16 + 8] = nvb;
      }
    }

    // epilogue: divide by l, store fp32
    f32x4 lv;
    #pragma unroll
    for (int rr = 0; rr < 4; ++rr) lv[rr] = 1.f / __shfl(l_i, quad * 4 + rr);
    float* op = out + ((size_t)(b * NT + q0 + wq * 16 + quad * 4)) * NH + l16;
    #pragma unroll
    for (int nt = 0; nt < 4; ++nt)
      #pragma unroll
      for (int rr = 0; rr < 4; ++rr)
        op[(size_t)rr * NH + nt * 16] = o[nt][rr] * lv[rr];
  }
}

extern "C" void kernel_launch(void* const* d_in, const int* in_sizes, int n_in,
                              void* d_out, int out_size, void* d_ws, size_t ws_size,
                              hipStream_t stream) {
  const float* x  = (const float*)d_in[0];
  const float* Wk = (const float*)d_in[1];
  const float* Wq = (const float*)d_in[2];
  const float* Wv = (const float*)d_in[3];
  float* out = (float*)d_out;

  char* ws = (char*)d_ws;
  __bf16* Wt  = (__bf16*)ws;                       // 192*384*2 = 147,456 B
  __bf16* Qb  = (__bf16*)(ws + 256 * 1024);        // each 32*2048*64*2 = 8 MiB
  __bf16* Kb  = Qb + (size_t)NB * NT * NH;
  __bf16* Vtb = Kb + (size_t)NB * NT * NH;

  pack_w_kernel<<<288, 256, 0, stream>>>(Wk, Wq, Wv, Wt);
  qkv_kernel<<<1024, 256, 0, stream>>>(x, Wt, Qb, Kb, Vtb);
  attn_kernel<<<NB * 16, 256, 0, stream>>>(Qb, Kb, Vtb, out);
}

// Round 3
// 209.694 us; speedup vs baseline: 1.2248x; 1.1982x over previous
//
#include <hip/hip_runtime.h>

typedef __bf16 bf16_8 __attribute__((ext_vector_type(8)));
typedef __bf16 bf16_4 __attribute__((ext_vector_type(4)));
typedef float  f32x4  __attribute__((ext_vector_type(4)));

#define NB 32
#define NT 2048
#define NC 384
#define NH 64

static __device__ __forceinline__ f32x4 mfma16(bf16_8 a, bf16_8 b, f32x4 c) {
  return __builtin_amdgcn_mfma_f32_16x16x32_bf16(a, b, c, 0, 0, 0);
}

// ---- kernel 1: pack weights: fp32 [C,H] x3 -> bf16 Wt[n][k], n: 0-63=Q(Wq*0.125), 64-127=K, 128-191=V
__global__ void pack_w_kernel(const float* __restrict__ Wk, const float* __restrict__ Wq,
                              const float* __restrict__ Wv, __bf16* __restrict__ Wt) {
  int idx = blockIdx.x * 256 + threadIdx.x;
  if (idx >= 192 * NC) return;
  int n = idx / NC, k = idx % NC;
  int sel = n >> 6, h = n & 63;
  const float* W = (sel == 0) ? Wq : (sel == 1 ? Wk : Wv);
  float v = W[k * NH + h];
  if (sel == 0) v *= 0.125f;  // fold attention scale H^-0.5 (exact pow2)
  Wt[idx] = (__bf16)v;
}

// ---- kernel 2: QKV projection with the ENTIRE Wt in LDS (147,456 B, XOR-swizzled).
// Block = 1024 threads (16 waves), 256 rows/block, grid 256 = 1 block/CU.
// W-fragment reads: ds_read_b128 at 2-way bank aliasing (free). x: direct global,
// 1-deep prefetch; each x element read exactly once kernel-wide.
__launch_bounds__(1024, 4)
__global__ void qkv_kernel(const float* __restrict__ x, const __bf16* __restrict__ Wt,
                           __bf16* __restrict__ Q, __bf16* __restrict__ K,
                           __bf16* __restrict__ Vt) {
  __shared__ __bf16 Wl[192 * 384];  // 147,456 B; chunk c of row r stored at c^(r&7)

  const int tid  = threadIdx.x;
  const int lane = tid & 63, wq = tid >> 6;
  const int quad = lane >> 4, l16 = lane & 15;
  const int rowblk = blockIdx.x * 256;
  const int rbase  = rowblk + wq * 16;
  const int row    = rbase + l16;  // this lane's x row

  // stage Wt -> LDS, 16-B chunks, XOR swizzle. 9216 chunks / 1024 threads = 9 each.
  #pragma unroll
  for (int i = 0; i < 9; ++i) {
    int g = tid + i * 1024;
    int r = g / 48, c = g - r * 48;
    int p = c ^ (r & 7);
    uint4 v = ((const uint4*)Wt)[g];
    *(uint4*)&Wl[(r * 48 + p) * 8] = v;
  }
  __syncthreads();

  f32x4 acc[12];
  #pragma unroll
  for (int n = 0; n < 12; ++n) acc[n] = f32x4{0.f, 0.f, 0.f, 0.f};

  const float* xrow = x + (size_t)row * NC;
  f32x4 x0 = *(const f32x4*)(xrow + quad * 8);
  f32x4 x1 = *(const f32x4*)(xrow + quad * 8 + 4);

  #pragma unroll
  for (int kc = 0; kc < 12; ++kc) {
    f32x4 nx0, nx1;
    if (kc < 11) {  // prefetch next x slab before the MFMA chain
      const float* xp = xrow + (kc + 1) * 32 + quad * 8;
      nx0 = *(const f32x4*)xp;
      nx1 = *(const f32x4*)(xp + 4);
    }
    bf16_8 a;
    a[0] = (__bf16)x0[0]; a[1] = (__bf16)x0[1]; a[2] = (__bf16)x0[2]; a[3] = (__bf16)x0[3];
    a[4] = (__bf16)x1[0]; a[5] = (__bf16)x1[1]; a[6] = (__bf16)x1[2]; a[7] = (__bf16)x1[3];
    const int pc = (kc * 4 + quad) ^ (l16 & 7);  // swizzled chunk within row
    const int cbase = l16 * 48 + pc;             // row l16 (+ n*16 rows below)
    #pragma unroll
    for (int n = 0; n < 12; ++n) {
      bf16_8 b = *(const bf16_8*)&Wl[(n * 16 * 48 + cbase) * 8];
      acc[n] = mfma16(a, b, acc[n]);
    }
    x0 = nx0; x1 = nx1;
  }

  // Q, K direct stores (C-layout: row=quad*4+r, col=l16)
  #pragma unroll
  for (int n = 0; n < 8; ++n)
    #pragma unroll
    for (int r = 0; r < 4; ++r) {
      int orow = rbase + quad * 4 + r;
      int h = (n & 3) * 16 + l16;
      __bf16 bv = (__bf16)acc[n][r];
      if (n < 4) Q[(size_t)orow * NH + h] = bv;
      else       K[(size_t)orow * NH + h] = bv;
    }

  // V transpose: reuse the W LDS region (all waves done reading W after barrier)
  __syncthreads();
  __bf16 (*Vl)[264] = (__bf16(*)[264])Wl;  // [h][t_local 256 + pad8] = 33,792 B
  #pragma unroll
  for (int n = 8; n < 12; ++n) {
    int h = (n - 8) * 16 + l16;
    int t0 = wq * 16 + quad * 4;
    bf16_4 p;
    p[0] = (__bf16)acc[n][0]; p[1] = (__bf16)acc[n][1];
    p[2] = (__bf16)acc[n][2]; p[3] = (__bf16)acc[n][3];
    *(bf16_4*)&Vl[h][t0] = p;
  }
  __syncthreads();
  {
    int h = tid >> 4, seg = tid & 15;  // consecutive lanes -> consecutive t: coalesced
    int bb = rowblk >> 11, t0 = (rowblk & (NT - 1)) + seg * 16;
    const __bf16* src = &Vl[h][seg * 16];
    __bf16* dst = Vt + ((size_t)(bb * NH + h)) * NT + t0;
    ((uint4*)dst)[0] = ((const uint4*)src)[0];
    ((uint4*)dst)[1] = ((const uint4*)src)[1];
  }
}

// ---- kernel 3: flash attention, fold-paired for uniform work. (unchanged this round)
__launch_bounds__(256)
__global__ void attn_kernel(const __bf16* __restrict__ Q, const __bf16* __restrict__ K,
                            const __bf16* __restrict__ Vt, float* __restrict__ out) {
  __shared__ __bf16 Ks[2][64][72];    // [buf][s][h]
  __shared__ __bf16 Vs[2][64][72];    // [buf][h][s]
  __shared__ __bf16 Ps[4][16][72];    // per-wave P[q][s]

  const int tid  = threadIdx.x;
  const int lane = tid & 63, wq = tid >> 6;
  const int quad = lane >> 4, l16 = lane & 15;
  const int b    = blockIdx.x >> 4;
  const int pair = blockIdx.x & 15;

  const float NEG_INF = -__builtin_inff();
  const int r = tid >> 2, seg = tid & 3;  // staging: 4 threads per 64-elem row
  const __bf16* Kg = K  + (size_t)b * NT * NH;
  const __bf16* Vg = Vt + (size_t)b * NH * NT;

  for (int pass = 0; pass < 2; ++pass) {
    const int qt = pass ? pair : (31 - pair);
    const int q0 = qt * 64;
    const int nIter = qt + 1;

    // Q B-operand fragments (scale pre-folded into Wq)
    const __bf16* qrow = Q + ((size_t)(b * NT + q0 + wq * 16 + l16)) * NH + quad * 8;
    bf16_8 qf0 = *(const bf16_8*)qrow;
    bf16_8 qf1 = *(const bf16_8*)(qrow + 32);

    f32x4 o[4];
    #pragma unroll
    for (int i = 0; i < 4; ++i) o[i] = f32x4{0.f, 0.f, 0.f, 0.f};
    float m_i = NEG_INF, l_i = 0.f;

    __syncthreads();  // previous pass's readers done before restaging buf0

    // prologue: stage tile 0 into buf 0
    {
      const uint4* sK = (const uint4*)(Kg + (size_t)r * NH + seg * 16);
      uint4 ka = sK[0], kb = sK[1];
      const uint4* sV = (const uint4*)(Vg + (size_t)r * NT + seg * 16);
      uint4 va = sV[0], vb = sV[1];
      *(uint4*)&Ks[0][r][seg * 16]     = ka;
      *(uint4*)&Ks[0][r][seg * 16 + 8] = kb;
      *(uint4*)&Vs[0][r][seg * 16]     = va;
      *(uint4*)&Vs[0][r][seg * 16 + 8] = vb;
    }

    for (int i = 0; i < nIter; ++i) {
      const int cur = i & 1;
      const bool more = (i + 1 < nIter);
      uint4 nka, nkb, nva, nvb;
      if (more) {  // issue next tile's global loads; they fly across the barrier
        const int s0n = (i + 1) * 64;
        const uint4* sK = (const uint4*)(Kg + (size_t)(s0n + r) * NH + seg * 16);
        nka = sK[0]; nkb = sK[1];
        const uint4* sV = (const uint4*)(Vg + (size_t)r * NT + s0n + seg * 16);
        nva = sV[0]; nvb = sV[1];
      }
      __syncthreads();  // buf[cur] fully staged

      // S^T tiles: A=K rows (m=s), B=Q^T (n=q). D[s=quad*4+rr][q=l16]
      f32x4 s[4];
      #pragma unroll
      for (int st = 0; st < 4; ++st) {
        bf16_8 a0 = *(const bf16_8*)&Ks[cur][st * 16 + l16][quad * 8];
        bf16_8 a1 = *(const bf16_8*)&Ks[cur][st * 16 + l16][quad * 8 + 32];
        f32x4 accv = f32x4{0.f, 0.f, 0.f, 0.f};
        accv = mfma16(a0, qf0, accv);
        accv = mfma16(a1, qf1, accv);
        s[st] = accv;
      }

      if (i == qt) {  // diagonal tile: causal mask
        int qg = wq * 16 + l16;
        #pragma unroll
        for (int st = 0; st < 4; ++st)
          #pragma unroll
          for (int rr = 0; rr < 4; ++rr) {
            int sg = st * 16 + quad * 4 + rr;
            if (sg > qg) s[st][rr] = NEG_INF;
          }
      }

      // online softmax: all 16 values in-lane share q=l16
      float mx = NEG_INF;
      #pragma unroll
      for (int st = 0; st < 4; ++st)
        #pragma unroll
        for (int rr = 0; rr < 4; ++rr) mx = fmaxf(mx, s[st][rr]);
      mx = fmaxf(mx, __shfl_xor(mx, 16));
      mx = fmaxf(mx, __shfl_xor(mx, 32));
      float m_new = fmaxf(m_i, mx);
      float alpha = __expf(m_i - m_new);

      float lsum = 0.f;
      #pragma unroll
      for (int st = 0; st < 4; ++st) {
        bf16_4 pk;
        #pragma unroll
        for (int rr = 0; rr < 4; ++rr) {
          float p = __expf(s[st][rr] - m_new);
          lsum += p;
          pk[rr] = (__bf16)p;
        }
        *(bf16_4*)&Ps[wq][l16][st * 16 + quad * 4] = pk;
      }
      lsum += __shfl_xor(lsum, 16);
      lsum += __shfl_xor(lsum, 32);
      l_i = l_i * alpha + lsum;
      m_i = m_new;

      // rescale O (C-layout row q = quad*4+rr)
      f32x4 av;
      #pragma unroll
      for (int rr = 0; rr < 4; ++rr) av[rr] = __shfl(alpha, quad * 4 + rr);
      #pragma unroll
      for (int nt = 0; nt < 4; ++nt)
        #pragma unroll
        for (int rr = 0; rr < 4; ++rr) o[nt][rr] *= av[rr];

      // PV: A = P (own wave's LDS), B = V from Vs[cur][h][s]
      bf16_8 pa0 = *(const bf16_8*)&Ps[wq][l16][quad * 8];
      bf16_8 pa1 = *(const bf16_8*)&Ps[wq][l16][quad * 8 + 32];
      #pragma unroll
      for (int nt = 0; nt < 4; ++nt) {
        bf16_8 b0 = *(const bf16_8*)&Vs[cur][nt * 16 + l16][quad * 8];
        bf16_8 b1 = *(const bf16_8*)&Vs[cur][nt * 16 + l16][quad * 8 + 32];
        o[nt] = mfma16(pa0, b0, o[nt]);
        o[nt] = mfma16(pa1, b1, o[nt]);
      }

      if (more) {  // write next tile into the other buffer (no one reads it now)
        *(uint4*)&Ks[1 - cur][r][seg * 16]     = nka;
        *(uint4*)&Ks[1 - cur][r][seg * 16 + 8] = nkb;
        *(uint4*)&Vs[1 - cur][r][seg * 16]     = nva;
        *(uint4*)&Vs[1 - cur][r][seg * 16 + 8] = nvb;
      }
    }

    // epilogue: divide by l, store fp32
    f32x4 lv;
    #pragma unroll
    for (int rr = 0; rr < 4; ++rr) lv[rr] = 1.f / __shfl(l_i, quad * 4 + rr);
    float* op = out + ((size_t)(b * NT + q0 + wq * 16 + quad * 4)) * NH + l16;
    #pragma unroll
    for (int nt = 0; nt < 4; ++nt)
      #pragma unroll
      for (int rr = 0; rr < 4; ++rr)
        op[(size_t)rr * NH + nt * 16] = o[nt][rr] * lv[rr];
  }
}

extern "C" void kernel_launch(void* const* d_in, const int* in_sizes, int n_in,
                              void* d_out, int out_size, void* d_ws, size_t ws_size,
                              hipStream_t stream) {
  const float* x  = (const float*)d_in[0];
  const float* Wk = (const float*)d_in[1];
  const float* Wq = (const float*)d_in[2];
  const float* Wv = (const float*)d_in[3];
  float* out = (float*)d_out;

  char* ws = (char*)d_ws;
  __bf16* Wt  = (__bf16*)ws;                       // 192*384*2 = 147,456 B
  __bf16* Qb  = (__bf16*)(ws + 256 * 1024);        // each 32*2048*64*2 = 8 MiB
  __bf16* Kb  = Qb + (size_t)NB * NT * NH;
  __bf16* Vtb = Kb + (size_t)NB * NT * NH;

  pack_w_kernel<<<288, 256, 0, stream>>>(Wk, Wq, Wv, Wt);
  qkv_kernel<<<256, 1024, 0, stream>>>(x, Wt, Qb, Kb, Vtb);
  attn_kernel<<<NB * 16, 256, 0, stream>>>(Qb, Kb, Vtb, out);
}